// Round 5
// baseline (55991.998 us; speedup 1.0000x reference)
//
#include <hip/hip_runtime.h>

#define T_STEPS 512
#define BATCH 64
#define DIM 1024
#define HID 1024
#define NLAYER 2

typedef __attribute__((ext_vector_type(8))) short bf16x8;
typedef __attribute__((ext_vector_type(4))) float f32x4;
typedef unsigned short u16;
typedef unsigned int u32;

__device__ inline float bf2f(u16 u){ u32 v=((u32)u)<<16; float f; __builtin_memcpy(&f,&v,4); return f; }
__device__ inline u16 f2bf(float f){ u32 u; __builtin_memcpy(&u,&f,4); u = (u + 0x7fffu + ((u>>16)&1u))>>16; return (u16)u; }
__device__ inline float sigm(float x){ return 1.f/(1.f+__expf(-x)); }

// Coherent (L3-point) relaxed accessors: sc0 sc1, NO cache maintenance ops.
__device__ inline u32 ld_cc(const u32* p){ return __hip_atomic_load(p, __ATOMIC_RELAXED, __HIP_MEMORY_SCOPE_SYSTEM); }
__device__ inline void st_cc(u32* p, u32 v){ __hip_atomic_store(p, v, __ATOMIC_RELAXED, __HIP_MEMORY_SCOPE_SYSTEM); }
__device__ inline bf16x8 ld_frag_cc(const u16* p){
  union{ u32 w[4]; bf16x8 v; } u;
  const u32* q=(const u32*)p;
  u.w[0]=ld_cc(q); u.w[1]=ld_cc(q+1); u.w[2]=ld_cc(q+2); u.w[3]=ld_cc(q+3);
  return u.v;
}

// ---------------- fp32 -> bf16 cast ----------------
__global__ void cast_f2bf(const float* __restrict__ src, u16* __restrict__ dst, int n4){
  int i = blockIdx.x*blockDim.x + threadIdx.x;
  int stride = gridDim.x*blockDim.x;
  for(; i<n4; i+=stride){
    float4 v = ((const float4*)src)[i];
    ushort4 o; o.x=f2bf(v.x); o.y=f2bf(v.y); o.z=f2bf(v.z); o.w=f2bf(v.w);
    ((ushort4*)dst)[i]=o;
  }
}

// ---------------- transpose + cast: src fp32 [R][C] -> dst bf16 [C][R] ----------------
__global__ void transpose_cast(const float* __restrict__ src, u16* __restrict__ dst, int R, int C){
  __shared__ float tile[32][33];
  int c0 = blockIdx.x*32, r0 = blockIdx.y*32;
  int tx = threadIdx.x, ty = threadIdx.y;
  for(int i=ty;i<32;i+=8) tile[i][tx] = src[(size_t)(r0+i)*C + c0+tx];
  __syncthreads();
  for(int i=ty;i<32;i+=8) dst[(size_t)(c0+i)*R + r0+tx] = f2bf(tile[tx][i]);
}

// ---------------- bias2 = bhh @ Wg + bg  (per layer, [3H]) ----------------
__global__ void bias2_kernel(const u16* __restrict__ Wg_t, const float* __restrict__ bhh,
                             const float* __restrict__ bg, float* __restrict__ bias2){
  int w = (blockIdx.x*blockDim.x + threadIdx.x)>>6;
  int lane = threadIdx.x&63;
  if(w >= 3*HID) return;
  float s=0.f;
  for(int j=lane;j<HID;j+=64) s += bf2f(Wg_t[(size_t)w*HID + j]) * bhh[j];
  for(int off=32;off;off>>=1) s += __shfl_down(s, off);
  if(lane==0) bias2[w] = s + bg[w];
}

// ---------------- bf16 GEMM: C[M][N] = A[M][K] @ Bt[N][K]^T + bias[N] ----------------
template<int MODE>
__launch_bounds__(256)
__global__ void gemm_bt(const u16* __restrict__ A, const u16* __restrict__ Bt,
                        const float* __restrict__ bias, u16* __restrict__ Cmat,
                        int M, int N, int K, u16* planes, size_t PS){
  __shared__ __align__(16) u16 As[128*32];
  __shared__ __align__(16) u16 Bs[128*32];
  const int tid=threadIdx.x, lane=tid&63, wave=tid>>6;
  const size_t m0 = (size_t)blockIdx.y*128, n0=(size_t)blockIdx.x*128;
  const int wr=wave>>1, wc=wave&1, fr=lane&15, fq=lane>>4;
  f32x4 acc[4][4];
  for(int m=0;m<4;m++) for(int n=0;n<4;n++) acc[m][n]=(f32x4){0.f,0.f,0.f,0.f};
  const int nk = K>>5;
  for(int kt=0;kt<nk;kt++){
    __syncthreads();
    for(int j=0;j<2;j++){
      int c = tid + j*256; int row=c>>2; int ko=(c&3)*8;
      *(int4*)&As[row*32+ko] = *(const int4*)&A[(m0+row)*K + kt*32+ko];
      *(int4*)&Bs[row*32+ko] = *(const int4*)&Bt[(n0+row)*K + kt*32+ko];
    }
    __syncthreads();
    bf16x8 af[4], bfv[4];
    for(int m=0;m<4;m++) af[m]=*(const bf16x8*)&As[(wr*64+m*16+fr)*32 + fq*8];
    for(int n=0;n<4;n++) bfv[n]=*(const bf16x8*)&Bs[(wc*64+n*16+fr)*32 + fq*8];
    for(int m=0;m<4;m++)
      for(int n=0;n<4;n++)
        acc[m][n]=__builtin_amdgcn_mfma_f32_16x16x32_bf16(af[m],bfv[n],acc[m][n],0,0,0);
  }
  for(int n=0;n<4;n++){
    size_t colg = n0 + wc*64+n*16+fr;
    float bv = bias[colg];
    for(int m=0;m<4;m++){
      for(int r=0;r<4;r++){
        size_t rowg = m0 + wr*64+m*16+fq*4+r;
        float v = acc[m][n][r]+bv;
        if constexpr (MODE==0){
          Cmat[rowg*N + colg] = f2bf(v);
        } else if constexpr (MODE==1){
          size_t p = colg>>10, pc = colg&1023;
          planes[p*PS + rowg*HID + pc] = f2bf(v);
        } else {
          size_t p = colg>>10, pc = colg&1023;
          u16* dst = planes + (2+p)*PS + rowg*HID + pc;
          *dst = f2bf(v + bf2f(*dst));
        }
      }
    }
  }
}

// ---------------- fence-free flag barrier (64 blocks) ----------------
// Each wave drains vmcnt(0) (sc0sc1 stores ack'd at coherence point), syncs,
// block 0-thread stores its flag (relaxed system atomic), 64 lanes spin on the
// 64 flags with relaxed loads (cache-bypassing, always fresh). NO threadfence,
// NO acquire/release => no L2 writeback/invalidate walks.
__device__ inline void grid_barrier(u32* flags, u32 target){
  asm volatile("s_waitcnt vmcnt(0)" ::: "memory");
  __syncthreads();
  if(threadIdx.x==0)
    st_cc(&flags[(size_t)blockIdx.x*32], target);
  if(threadIdx.x<64){
    while(ld_cc(&flags[(size_t)threadIdx.x*32]) < target)
      __builtin_amdgcn_s_sleep(2);
  }
  __syncthreads();
  asm volatile("" ::: "memory");
}

// ---------------- persistent recurrent kernel: one layer, T steps, 2 barriers/step ----
// 64 blocks x 256 threads, plain launch. Block cj owns cols [16cj,16cj+16);
// wave w owns batch rows [16w,16w+16). Weights via normal loads (stay L2-hot
// forever); h/m exchanged via relaxed system-scope atomics (L3 coherence point).
__launch_bounds__(256, 1)
__global__ void mlstm_rec(const u16* __restrict__ xmi_p, const u16* __restrict__ xhi_p,
   const u16* __restrict__ xgi_p, const u16* __restrict__ xgo_p, const u16* __restrict__ xgf_p,
   const u16* __restrict__ Wmh_t, const u16* __restrict__ Whh_t, const u16* __restrict__ WhhG_t,
   const float* __restrict__ bmh, const float* __restrict__ bhh,
   u16* h_buf, float* c_buf, u16* m_buf,
   u16* seq_bf, float* seq_f32, float* hn, float* cn, u32* flags, int is_first)
{
  const int tid=threadIdx.x, lane=tid&63, wave=tid>>6;
  const int cb = blockIdx.x*16;
  const int rowbase = wave*16;
  const int fr=lane&15, fq=lane>>4;
  const int col = cb+fr;
  const u32 a_off = (u32)(rowbase+fr)*HID + fq*8;     // activation fragment base (u16 units)
  const size_t w_off = (size_t)col*HID + fq*8;        // weight fragment base (u16 units)

  float c_reg[4], h4[4];
  if(is_first){ for(int r=0;r<4;r++) c_reg[r]=0.f; }
  else { for(int r=0;r<4;r++) c_reg[r]=c_buf[(size_t)(rowbase+fq*4+r)*HID+col]; }
  for(int r=0;r<4;r++) h4[r]=0.f;

  const float bmh_c=bmh[col], bhh_c=bhh[col];
  u32 bar=0;

  // prologue: xp loads for t=0
  float xmi[4],xhi[4],xgi[4],xgo[4],xgf[4];
  #pragma unroll
  for(int r=0;r<4;r++){
    size_t idx = (size_t)(rowbase+fq*4+r)*HID + col;
    xmi[r]=bf2f(xmi_p[idx]); xhi[r]=bf2f(xhi_p[idx]);
    xgi[r]=bf2f(xgi_p[idx]); xgo[r]=bf2f(xgo_p[idx]); xgf[r]=bf2f(xgf_p[idx]);
  }

  for(int t=0;t<T_STEPS;t++){
    // ---- Stage A: m = xmi * (h @ Wmh + bmh)
    f32x4 a0={0.f,0.f,0.f,0.f}, a1={0.f,0.f,0.f,0.f};
    #pragma unroll 4
    for(int kt=0;kt<32;kt+=2){
      bf16x8 av0=ld_frag_cc(h_buf + a_off + kt*32);
      bf16x8 av1=ld_frag_cc(h_buf + a_off + kt*32+32);
      bf16x8 wv0=*(const bf16x8*)(Wmh_t + w_off + kt*32);
      bf16x8 wv1=*(const bf16x8*)(Wmh_t + w_off + kt*32+32);
      a0=__builtin_amdgcn_mfma_f32_16x16x32_bf16(av0,wv0,a0,0,0,0);
      a1=__builtin_amdgcn_mfma_f32_16x16x32_bf16(av1,wv1,a1,0,0,0);
    }
    #pragma unroll
    for(int r=0;r<4;r++){
      u32 my = (u32)f2bf(xmi[r]*(a0[r]+a1[r]+bmh_c));
      u32 ot = (u32)__shfl_xor((int)my, 1);
      if((lane&1)==0){
        int row=rowbase+fq*4+r;
        st_cc((u32*)(m_buf + (size_t)row*HID + col), my | (ot<<16));
      }
    }
    bar++; grid_barrier(flags,bar);

    // ---- prefetch xp for t+1 (normal loads; complete by end-of-step vmcnt)
    float nmi[4],nhi[4],ngi[4],ngo[4],ngf[4];
    {
      size_t tb2 = (size_t)((t+1<T_STEPS)?(t+1):t)*BATCH*HID;
      #pragma unroll
      for(int r=0;r<4;r++){
        size_t idx = tb2 + (size_t)(rowbase+fq*4+r)*HID + col;
        nmi[r]=bf2f(xmi_p[idx]); nhi[r]=bf2f(xhi_p[idx]);
        ngi[r]=bf2f(xgi_p[idx]); ngo[r]=bf2f(xgo_p[idx]); ngf[r]=bf2f(xgf_p[idx]);
      }
    }

    // ---- Stage B: [g|i|o|f] = m @ [Whh|WhhG]; gates; state update
    f32x4 ag={0.f,0.f,0.f,0.f}, ai={0.f,0.f,0.f,0.f}, ao={0.f,0.f,0.f,0.f}, af={0.f,0.f,0.f,0.f};
    #pragma unroll 4
    for(int kt=0;kt<32;kt++){
      bf16x8 mv = ld_frag_cc(m_buf + a_off + kt*32);
      bf16x8 w0 = *(const bf16x8*)(Whh_t  + w_off + kt*32);
      bf16x8 w1 = *(const bf16x8*)(WhhG_t + w_off + kt*32);
      bf16x8 w2 = *(const bf16x8*)(WhhG_t + (size_t)HID*HID + w_off + kt*32);
      bf16x8 w3 = *(const bf16x8*)(WhhG_t + (size_t)2*HID*HID + w_off + kt*32);
      ag=__builtin_amdgcn_mfma_f32_16x16x32_bf16(mv,w0,ag,0,0,0);
      ai=__builtin_amdgcn_mfma_f32_16x16x32_bf16(mv,w1,ai,0,0,0);
      ao=__builtin_amdgcn_mfma_f32_16x16x32_bf16(mv,w2,ao,0,0,0);
      af=__builtin_amdgcn_mfma_f32_16x16x32_bf16(mv,w3,af,0,0,0);
    }
    const size_t tb = (size_t)t*BATCH*HID;
    #pragma unroll
    for(int r=0;r<4;r++){
      int row=rowbase+fq*4+r;
      float g  = ag[r]+bhh_c+xhi[r];
      float iv = sigm(ai[r]+xgi[r]);
      float ov = sigm(ao[r]+xgo[r]);
      float fv = sigm(af[r]+xgf[r]);
      c_reg[r]=fv*c_reg[r]+iv*tanhf(g);
      h4[r]=tanhf(c_reg[r])*ov;
      if(seq_bf) seq_bf[tb + (size_t)row*HID+col]=f2bf(h4[r]);
      else       seq_f32[tb + (size_t)row*HID+col]=h4[r];
    }
    #pragma unroll
    for(int r=0;r<4;r++){
      u32 my = (u32)f2bf(h4[r]);
      u32 ot = (u32)__shfl_xor((int)my, 1);
      if((lane&1)==0){
        int row=rowbase+fq*4+r;
        st_cc((u32*)(h_buf + (size_t)row*HID + col), my | (ot<<16));
      }
    }
    #pragma unroll
    for(int r=0;r<4;r++){ xmi[r]=nmi[r]; xhi[r]=nhi[r]; xgi[r]=ngi[r]; xgo[r]=ngo[r]; xgf[r]=ngf[r]; }
    bar++; grid_barrier(flags,bar);
  }
  for(int r=0;r<4;r++){
    int row=rowbase+fq*4+r;
    hn[(size_t)row*HID+col]=h4[r];
    cn[(size_t)row*HID+col]=c_reg[r];
    if(is_first) c_buf[(size_t)row*HID+col]=c_reg[r];
  }
}

extern "C" void kernel_launch(void* const* d_in, const int* in_sizes, int n_in,
                              void* d_out, int out_size, void* d_ws, size_t ws_size,
                              hipStream_t stream){
  const float* x   = (const float*)d_in[0];
  const float* Wx  = (const float*)d_in[1];
  const float* bx  = (const float*)d_in[2];
  const float* Wmh = (const float*)d_in[3];
  const float* bmh = (const float*)d_in[4];
  const float* Whh = (const float*)d_in[5];
  const float* bhh = (const float*)d_in[6];
  const float* Wg  = (const float*)d_in[7];
  const float* bg  = (const float*)d_in[8];
  float* out = (float*)d_out;
  char* ws = (char*)d_ws;

  const size_t TB = (size_t)T_STEPS*BATCH;
  const size_t PS = TB*HID;           // plane stride (elements)

  size_t off=0;
  auto alloc=[&](size_t b){ size_t o=off; off += (b+255)&~(size_t)255; return o; };
  size_t planes_off = alloc(5*PS*2);                        // 335.5 MB
  size_t seq_off  = alloc(PS*2);                            // 67 MB
  size_t wx_off   = alloc((size_t)NLAYER*5*HID*DIM*2);      // 21 MB
  size_t wmh_off  = alloc((size_t)NLAYER*HID*HID*2);
  size_t whh_off  = alloc((size_t)NLAYER*HID*HID*2);
  size_t wg_off   = alloc((size_t)NLAYER*3*HID*HID*2);
  size_t whhp_off = alloc((size_t)NLAYER*HID*HID*2);        // Whh plain bf16
  size_t whhg_off = alloc((size_t)3*HID*HID*2);             // WhhG_t (per-layer reuse)
  size_t bias2_off= alloc((size_t)3*HID*4);
  size_t zeros_off= alloc(4096);
  size_t h_off    = alloc((size_t)BATCH*HID*2);
  size_t m_off    = alloc((size_t)BATCH*HID*2);
  size_t c_off    = alloc((size_t)BATCH*HID*4);
  size_t flag_off = alloc(16384);
  (void)ws_size;

  u16* planes_p = (u16*)(ws+planes_off);
  u16* seq_p  = (u16*)(ws+seq_off);
  u16* wx_p   = (u16*)(ws+wx_off);
  u16* wmh_p  = (u16*)(ws+wmh_off);
  u16* whh_p  = (u16*)(ws+whh_off);
  u16* wg_p   = (u16*)(ws+wg_off);
  u16* whhpl_p= (u16*)(ws+whhp_off);
  u16* whhg_p = (u16*)(ws+whhg_off);
  float* bias2_p = (float*)(ws+bias2_off);
  float* zeros_p = (float*)(ws+zeros_off);
  u16* h_p  = (u16*)(ws+h_off);
  u16* m_p  = (u16*)(ws+m_off);
  float* c_p= (float*)(ws+c_off);
  u32* flags_p= (u32*)(ws+flag_off);

  hipMemsetAsync(h_p, 0, (size_t)BATCH*HID*2, stream);
  hipMemsetAsync(flags_p, 0, 16384, stream);
  hipMemsetAsync(zeros_p, 0, 4096, stream);

  cast_f2bf<<<4096,256,0,stream>>>(x, seq_p, T_STEPS*BATCH*DIM/4);
  cast_f2bf<<<2048,256,0,stream>>>(Whh, whhpl_p, NLAYER*HID*HID/4);

  for(int l=0;l<NLAYER;l++){
    transpose_cast<<<dim3(5*HID/32, DIM/32), dim3(32,8),0,stream>>>(
        Wx + (size_t)l*DIM*5*HID, wx_p + (size_t)l*5*HID*DIM, DIM, 5*HID);
    transpose_cast<<<dim3(HID/32, HID/32), dim3(32,8),0,stream>>>(
        Wmh + (size_t)l*HID*HID, wmh_p + (size_t)l*HID*HID, HID, HID);
    transpose_cast<<<dim3(HID/32, HID/32), dim3(32,8),0,stream>>>(
        Whh + (size_t)l*HID*HID, whh_p + (size_t)l*HID*HID, HID, HID);
    transpose_cast<<<dim3(3*HID/32, HID/32), dim3(32,8),0,stream>>>(
        Wg + (size_t)l*HID*3*HID, wg_p + (size_t)l*3*HID*HID, HID, 3*HID);
  }

  float* seq_out_f32 = out;                                  // [T,B,H]
  float* hn_out = out + PS;                                  // [L,B,H]
  float* cn_out = hn_out + (size_t)NLAYER*BATCH*HID;         // [L,B,H]

  for(int l=0;l<NLAYER;l++){
    const u16* wg_l = wg_p + (size_t)l*3*HID*HID;
    // bias2 = bhh @ Wg + bg
    bias2_kernel<<<768,256,0,stream>>>(wg_l, bhh + (size_t)l*HID, bg + (size_t)l*3*HID, bias2_p);
    // WhhG_t[3H][H]: WhhG_t[n][k] = sum_j Wg[j][n]*Whh[k][j]  ((m@Whh)@Wg == m@WhhG)
    gemm_bt<0><<<dim3(HID/128, 3*HID/128),256,0,stream>>>(
        wg_l, whhpl_p + (size_t)l*HID*HID, zeros_p, whhg_p,
        3*HID, HID, HID, nullptr, 0);
    // xp planes: [mi|hi|ii|oi|fi]
    gemm_bt<1><<<dim3(5*HID/128, (int)(TB/128)),256,0,stream>>>(
        seq_p, wx_p+(size_t)l*5*HID*DIM, bx + (size_t)l*5*HID, nullptr,
        (int)TB, 5*HID, DIM, planes_p, PS);
    // XG fuse: planes[2..4] += hi@Wg + bias2
    gemm_bt<2><<<dim3(3*HID/128, (int)(TB/128)),256,0,stream>>>(
        planes_p + PS, wg_l, bias2_p, nullptr,
        (int)TB, 3*HID, HID, planes_p, PS);

    const u16* xmi_c = planes_p;
    const u16* xhi_c = planes_p + PS;
    const u16* xgi_c = planes_p + 2*PS;
    const u16* xgo_c = planes_p + 3*PS;
    const u16* xgf_c = planes_p + 4*PS;
    const u16* wm_c = wmh_p + (size_t)l*HID*HID;
    const u16* wh_c = whh_p + (size_t)l*HID*HID;
    const u16* wG_c = whhg_p;
    const float* bmh_l = bmh + (size_t)l*HID;
    const float* bhh_l = bhh + (size_t)l*HID;
    u16* seqbf = (l==0)? seq_p : (u16*)nullptr;
    float* seqf = (l==0)? (float*)nullptr : seq_out_f32;
    float* hn_l = hn_out + (size_t)l*BATCH*HID;
    float* cn_l = cn_out + (size_t)l*BATCH*HID;
    u32* flags_l = flags_p + (size_t)l*2048;
    int is_first = (l==0)?1:0;

    mlstm_rec<<<dim3(64), dim3(256), 0, stream>>>(
        xmi_c, xhi_c, xgi_c, xgo_c, xgf_c,
        wm_c, wh_c, wG_c,
        bmh_l, bhh_l,
        h_p, c_p, m_p,
        seqbf, seqf, hn_l, cn_l, flags_l, is_first);
  }
}

// Round 6
// 31408.923 us; speedup vs baseline: 1.7827x; 1.7827x over previous
//
#include <hip/hip_runtime.h>

#define T_STEPS 512
#define BATCH 64
#define DIM 1024
#define HID 1024
#define NLAYER 2
#define MFMA_B16 __builtin_amdgcn_mfma_f32_16x16x32_bf16

typedef __attribute__((ext_vector_type(8))) short bf16x8;
typedef __attribute__((ext_vector_type(4))) float f32x4;
typedef unsigned short u16;
typedef unsigned int u32;

__device__ inline float bf2f(u16 u){ u32 v=((u32)u)<<16; float f; __builtin_memcpy(&f,&v,4); return f; }
__device__ inline u16 f2bf(float f){ u32 u; __builtin_memcpy(&u,&f,4); u = (u + 0x7fffu + ((u>>16)&1u))>>16; return (u16)u; }
__device__ inline float sigm(float x){ return 1.f/(1.f+__expf(-x)); }

// Coherent (L2-bypassing) relaxed accessors.
__device__ inline u32 ld_cc(const u32* p){ return __hip_atomic_load(p, __ATOMIC_RELAXED, __HIP_MEMORY_SCOPE_SYSTEM); }
__device__ inline void st_cc(u32* p, u32 v){ __hip_atomic_store(p, v, __ATOMIC_RELAXED, __HIP_MEMORY_SCOPE_SYSTEM); }

// 8 wide coherent loads (512B span), one addr + imm offsets, no wait (caller waits).
__device__ __forceinline__ void ld8_sys(const u16* p, bf16x8* f){
  asm volatile(
    "global_load_dwordx4 %0, %8, off sc0 sc1\n\t"
    "global_load_dwordx4 %1, %8, off offset:64 sc0 sc1\n\t"
    "global_load_dwordx4 %2, %8, off offset:128 sc0 sc1\n\t"
    "global_load_dwordx4 %3, %8, off offset:192 sc0 sc1\n\t"
    "global_load_dwordx4 %4, %8, off offset:256 sc0 sc1\n\t"
    "global_load_dwordx4 %5, %8, off offset:320 sc0 sc1\n\t"
    "global_load_dwordx4 %6, %8, off offset:384 sc0 sc1\n\t"
    "global_load_dwordx4 %7, %8, off offset:448 sc0 sc1"
    : "=&v"(f[0]),"=&v"(f[1]),"=&v"(f[2]),"=&v"(f[3]),
      "=&v"(f[4]),"=&v"(f[5]),"=&v"(f[6]),"=&v"(f[7])
    : "v"(p)
    : "memory");
}
#define WAITV(S) do{ asm volatile("s_waitcnt vmcnt(" S ")" ::: "memory"); __builtin_amdgcn_sched_barrier(0); }while(0)

// ---------------- fp32 -> bf16 cast ----------------
__global__ void cast_f2bf(const float* __restrict__ src, u16* __restrict__ dst, int n4){
  int i = blockIdx.x*blockDim.x + threadIdx.x;
  int stride = gridDim.x*blockDim.x;
  for(; i<n4; i+=stride){
    float4 v = ((const float4*)src)[i];
    ushort4 o; o.x=f2bf(v.x); o.y=f2bf(v.y); o.z=f2bf(v.z); o.w=f2bf(v.w);
    ((ushort4*)dst)[i]=o;
  }
}

// ---------------- transpose + cast: src fp32 [R][C] -> dst bf16 [C][R] ----------------
__global__ void transpose_cast(const float* __restrict__ src, u16* __restrict__ dst, int R, int C){
  __shared__ float tile[32][33];
  int c0 = blockIdx.x*32, r0 = blockIdx.y*32;
  int tx = threadIdx.x, ty = threadIdx.y;
  for(int i=ty;i<32;i+=8) tile[i][tx] = src[(size_t)(r0+i)*C + c0+tx];
  __syncthreads();
  for(int i=ty;i<32;i+=8) dst[(size_t)(c0+i)*R + r0+tx] = f2bf(tile[tx][i]);
}

// ---------------- bias2 = bhh @ Wg + bg ----------------
__global__ void bias2_kernel(const u16* __restrict__ Wg_t, const float* __restrict__ bhh,
                             const float* __restrict__ bg, float* __restrict__ bias2){
  int w = (blockIdx.x*blockDim.x + threadIdx.x)>>6;
  int lane = threadIdx.x&63;
  if(w >= 3*HID) return;
  float s=0.f;
  for(int j=lane;j<HID;j+=64) s += bf2f(Wg_t[(size_t)w*HID + j]) * bhh[j];
  for(int off=32;off;off>>=1) s += __shfl_down(s, off);
  if(lane==0) bias2[w] = s + bg[w];
}

// ---------------- bf16 GEMM: C = A @ Bt^T + bias ----------------
// MODE 0: plain write Cmat[row*N+col]
// MODE 1: N=5H; write into packed layout [t][cj][p][b][16c]
// MODE 2: N=3H; A is the packed xhi plane (p=1); dst += packed planes 2..4
template<int MODE>
__launch_bounds__(256)
__global__ void gemm_bt(const u16* __restrict__ A, const u16* __restrict__ Bt,
                        const float* __restrict__ bias, u16* __restrict__ Cmat,
                        int M, int N, int K, u16* packed){
  __shared__ __align__(16) u16 As[128*32];
  __shared__ __align__(16) u16 Bs[128*32];
  const int tid=threadIdx.x, lane=tid&63, wave=tid>>6;
  const size_t m0 = (size_t)blockIdx.y*128, n0=(size_t)blockIdx.x*128;
  const int wr=wave>>1, wc=wave&1, fr=lane&15, fq=lane>>4;
  f32x4 acc[4][4];
  for(int m=0;m<4;m++) for(int n=0;n<4;n++) acc[m][n]=(f32x4){0.f,0.f,0.f,0.f};
  const int nk = K>>5;
  for(int kt=0;kt<nk;kt++){
    __syncthreads();
    for(int j=0;j<2;j++){
      int c = tid + j*256; int row=c>>2; int ko=(c&3)*8;
      if constexpr (MODE==2){
        size_t g = m0+row; int kc = kt*32+ko;
        size_t addr = (((g>>6)*64 + (size_t)(kc>>4))*5 + 1)*1024 + (g&63)*16 + (kc&15);
        *(int4*)&As[row*32+ko] = *(const int4*)&A[addr];
      } else {
        *(int4*)&As[row*32+ko] = *(const int4*)&A[(m0+row)*K + kt*32+ko];
      }
      *(int4*)&Bs[row*32+ko] = *(const int4*)&Bt[(n0+row)*K + kt*32+ko];
    }
    __syncthreads();
    bf16x8 af[4], bfv[4];
    for(int m=0;m<4;m++) af[m]=*(const bf16x8*)&As[(wr*64+m*16+fr)*32 + fq*8];
    for(int n=0;n<4;n++) bfv[n]=*(const bf16x8*)&Bs[(wc*64+n*16+fr)*32 + fq*8];
    for(int m=0;m<4;m++)
      for(int n=0;n<4;n++)
        acc[m][n]=MFMA_B16(af[m],bfv[n],acc[m][n],0,0,0);
  }
  for(int n=0;n<4;n++){
    size_t colg = n0 + wc*64+n*16+fr;
    float bv = bias[colg];
    for(int m=0;m<4;m++){
      for(int r=0;r<4;r++){
        size_t rowg = m0 + wr*64+m*16+fq*4+r;
        float v = acc[m][n][r]+bv;
        if constexpr (MODE==0){
          Cmat[rowg*N + colg] = f2bf(v);
        } else if constexpr (MODE==1){
          size_t p = colg>>10, pc = colg&1023;
          size_t t = rowg>>6, b = rowg&63, cj = pc>>4, c = pc&15;
          packed[((t*64+cj)*5 + p)*1024 + b*16 + c] = f2bf(v);
        } else {
          size_t pp = colg>>10, pc = colg&1023;
          size_t t = rowg>>6, b = rowg&63, cj = pc>>4, c = pc&15;
          u16* dst = packed + ((t*64+cj)*5 + (2+pp))*1024 + b*16 + c;
          *dst = f2bf(v + bf2f(*dst));
        }
      }
    }
  }
}

// ---------------- fence-free flag barrier (64 blocks) ----------------
__device__ inline void grid_barrier(u32* flags, u32 target){
  asm volatile("s_waitcnt vmcnt(0)" ::: "memory");
  __syncthreads();
  if(threadIdx.x==0)
    st_cc(&flags[(size_t)blockIdx.x*32], target);
  if(threadIdx.x<64){
    while(ld_cc(&flags[(size_t)threadIdx.x*32]) < target){}
  }
  __syncthreads();
}

// ---------------- persistent recurrent kernel ----------------
// 64 blocks x 256 threads. Block cj owns cols [16cj,16cj+16); wave w owns rows
// [16w,16w+16). Wmh in VGPRs; stage-B weights normal (L2-hot); h/m via batched
// wide sc0sc1 loads; xp via packed per-(t,block) 10KB chunk -> LDS dbuf.
__launch_bounds__(256, 1)
__global__ void mlstm_rec(const u16* __restrict__ xp_pack,
   const u16* __restrict__ Wmh_t, const u16* __restrict__ Whh_t, const u16* __restrict__ WhhG_t,
   const float* __restrict__ bmh, const float* __restrict__ bhh,
   u16* h_buf, float* c_buf, u16* m_buf,
   u16* seq_bf, float* seq_f32, float* hn, float* cn, u32* flags, int is_first)
{
  __shared__ __align__(16) u16 xl[2][5120];
  const int tid=threadIdx.x, lane=tid&63, wave=tid>>6;
  const int cj = blockIdx.x;
  const int rowbase = wave*16;
  const int fr=lane&15, fq=lane>>4;
  const int col = cj*16+fr;
  const u32 a_off = (u32)(rowbase+fr)*HID + fq*8;
  const size_t w_off = (size_t)col*HID + fq*8;

  bf16x8 wmh[32];
  #pragma unroll
  for(int kt=0;kt<32;kt++) wmh[kt] = *(const bf16x8*)(Wmh_t + w_off + kt*32);

  float c_reg[4], h4[4];
  if(is_first){ for(int r=0;r<4;r++) c_reg[r]=0.f; }
  else { for(int r=0;r<4;r++) c_reg[r]=c_buf[(size_t)(rowbase+fq*4+r)*HID+col]; }
  for(int r=0;r<4;r++) h4[r]=0.f;

  const float bmh_c=bmh[col], bhh_c=bhh[col];
  u32 bar=0; int buf=0;

  { // xp chunk for t=0
    const int4* s0 = (const int4*)(xp_pack + (size_t)cj*5120);
    int4* d0 = (int4*)xl[0];
    d0[tid]=s0[tid]; d0[tid+256]=s0[tid+256]; if(tid<128) d0[tid+512]=s0[tid+512];
  }
  __syncthreads();

  for(int t=0;t<T_STEPS;t++){
    // ---- Stage A: m = xmi * (h @ Wmh + bmh)
    bf16x8 hf[32];
    const u16* hb = h_buf + a_off;
    ld8_sys(hb, hf); ld8_sys(hb+256, hf+8); ld8_sys(hb+512, hf+16); ld8_sys(hb+768, hf+24);
    f32x4 a0={0.f,0.f,0.f,0.f}, a1={0.f,0.f,0.f,0.f};
    WAITV("24");
    #pragma unroll
    for(int kt=0;kt<8;kt+=2){ a0=MFMA_B16(hf[kt],wmh[kt],a0,0,0,0); a1=MFMA_B16(hf[kt+1],wmh[kt+1],a1,0,0,0); }
    WAITV("16");
    #pragma unroll
    for(int kt=8;kt<16;kt+=2){ a0=MFMA_B16(hf[kt],wmh[kt],a0,0,0,0); a1=MFMA_B16(hf[kt+1],wmh[kt+1],a1,0,0,0); }
    WAITV("8");
    #pragma unroll
    for(int kt=16;kt<24;kt+=2){ a0=MFMA_B16(hf[kt],wmh[kt],a0,0,0,0); a1=MFMA_B16(hf[kt+1],wmh[kt+1],a1,0,0,0); }
    WAITV("0");
    #pragma unroll
    for(int kt=24;kt<32;kt+=2){ a0=MFMA_B16(hf[kt],wmh[kt],a0,0,0,0); a1=MFMA_B16(hf[kt+1],wmh[kt+1],a1,0,0,0); }
    #pragma unroll
    for(int r=0;r<4;r++){
      int b = rowbase+fq*4+r;
      float xmiv = bf2f(xl[buf][b*16+fr]);
      u32 my=(u32)f2bf(xmiv*(a0[r]+a1[r]+bmh_c));
      u32 ot=(u32)__shfl_xor((int)my,1);
      if((lane&1)==0) st_cc((u32*)(m_buf+(size_t)b*HID+col), my|(ot<<16));
    }
    bar++; grid_barrier(flags,bar);

    // ---- Stage B: [g|i|o|f] = m @ [Whh|WhhG]; gates; state update
    int tn=(t+1<T_STEPS)?(t+1):t;
    const int4* s2=(const int4*)(xp_pack + (size_t)(tn*64+cj)*5120);
    int4 q0=s2[tid], q1=s2[tid+256], q2={0,0,0,0};
    if(tid<128) q2=s2[tid+512];
    bf16x8 mf[32];
    const u16* mb = m_buf + a_off;
    ld8_sys(mb, mf); ld8_sys(mb+256, mf+8); ld8_sys(mb+512, mf+16); ld8_sys(mb+768, mf+24);
    WAITV("0");
    f32x4 ag={0.f,0.f,0.f,0.f}, aiv={0.f,0.f,0.f,0.f}, aov={0.f,0.f,0.f,0.f}, afv={0.f,0.f,0.f,0.f};
    #pragma unroll
    for(int kt=0;kt<32;kt++){
      bf16x8 w0=*(const bf16x8*)(Whh_t  + w_off + kt*32);
      bf16x8 w1=*(const bf16x8*)(WhhG_t + w_off + kt*32);
      bf16x8 w2=*(const bf16x8*)(WhhG_t + (size_t)HID*HID + w_off + kt*32);
      bf16x8 w3=*(const bf16x8*)(WhhG_t + (size_t)2*HID*HID + w_off + kt*32);
      ag =MFMA_B16(mf[kt],w0,ag ,0,0,0);
      aiv=MFMA_B16(mf[kt],w1,aiv,0,0,0);
      aov=MFMA_B16(mf[kt],w2,aov,0,0,0);
      afv=MFMA_B16(mf[kt],w3,afv,0,0,0);
    }
    const size_t tb=(size_t)t*BATCH*HID;
    #pragma unroll
    for(int r=0;r<4;r++){
      int b=rowbase+fq*4+r;
      float g  = ag[r]+bhh_c+bf2f(xl[buf][1024+b*16+fr]);
      float iv = sigm(aiv[r]+bf2f(xl[buf][2048+b*16+fr]));
      float ov = sigm(aov[r]+bf2f(xl[buf][3072+b*16+fr]));
      float fv = sigm(afv[r]+bf2f(xl[buf][4096+b*16+fr]));
      c_reg[r]=fv*c_reg[r]+iv*tanhf(g);
      h4[r]=tanhf(c_reg[r])*ov;
      if(seq_bf) seq_bf[tb+(size_t)b*HID+col]=f2bf(h4[r]);
      else       seq_f32[tb+(size_t)b*HID+col]=h4[r];
    }
    #pragma unroll
    for(int r=0;r<4;r++){
      int b=rowbase+fq*4+r;
      u32 my=(u32)f2bf(h4[r]);
      u32 ot=(u32)__shfl_xor((int)my,1);
      if((lane&1)==0) st_cc((u32*)(h_buf+(size_t)b*HID+col), my|(ot<<16));
    }
    { int4* d2=(int4*)xl[buf^1]; d2[tid]=q0; d2[tid+256]=q1; if(tid<128) d2[tid+512]=q2; }
    bar++; grid_barrier(flags,bar);
    buf^=1;
  }
  for(int r=0;r<4;r++){
    int row=rowbase+fq*4+r;
    hn[(size_t)row*HID+col]=h4[r];
    cn[(size_t)row*HID+col]=c_reg[r];
    if(is_first) c_buf[(size_t)row*HID+col]=c_reg[r];
  }
}

extern "C" void kernel_launch(void* const* d_in, const int* in_sizes, int n_in,
                              void* d_out, int out_size, void* d_ws, size_t ws_size,
                              hipStream_t stream){
  const float* x   = (const float*)d_in[0];
  const float* Wx  = (const float*)d_in[1];
  const float* bx  = (const float*)d_in[2];
  const float* Wmh = (const float*)d_in[3];
  const float* bmh = (const float*)d_in[4];
  const float* Whh = (const float*)d_in[5];
  const float* bhh = (const float*)d_in[6];
  const float* Wg  = (const float*)d_in[7];
  const float* bg  = (const float*)d_in[8];
  float* out = (float*)d_out;
  char* ws = (char*)d_ws;

  const size_t TB = (size_t)T_STEPS*BATCH;
  const size_t PS = TB*HID;

  size_t off=0;
  auto alloc=[&](size_t b){ size_t o=off; off += (b+255)&~(size_t)255; return o; };
  size_t pack_off = alloc(5*PS*2);                          // 335.5 MB packed xp
  size_t seq_off  = alloc(PS*2);                            // 67 MB
  size_t wx_off   = alloc((size_t)NLAYER*5*HID*DIM*2);
  size_t wmh_off  = alloc((size_t)NLAYER*HID*HID*2);
  size_t whh_off  = alloc((size_t)NLAYER*HID*HID*2);
  size_t wg_off   = alloc((size_t)NLAYER*3*HID*HID*2);
  size_t whhp_off = alloc((size_t)NLAYER*HID*HID*2);
  size_t whhg_off = alloc((size_t)3*HID*HID*2);
  size_t bias2_off= alloc((size_t)3*HID*4);
  size_t zeros_off= alloc(4096);
  size_t h_off    = alloc((size_t)BATCH*HID*2);
  size_t m_off    = alloc((size_t)BATCH*HID*2);
  size_t c_off    = alloc((size_t)BATCH*HID*4);
  size_t flag_off = alloc(16384);
  (void)ws_size;

  u16* pack_p = (u16*)(ws+pack_off);
  u16* seq_p  = (u16*)(ws+seq_off);
  u16* wx_p   = (u16*)(ws+wx_off);
  u16* wmh_p  = (u16*)(ws+wmh_off);
  u16* whh_p  = (u16*)(ws+whh_off);
  u16* wg_p   = (u16*)(ws+wg_off);
  u16* whhpl_p= (u16*)(ws+whhp_off);
  u16* whhg_p = (u16*)(ws+whhg_off);
  float* bias2_p = (float*)(ws+bias2_off);
  float* zeros_p = (float*)(ws+zeros_off);
  u16* h_p  = (u16*)(ws+h_off);
  u16* m_p  = (u16*)(ws+m_off);
  float* c_p= (float*)(ws+c_off);
  u32* flags_p= (u32*)(ws+flag_off);

  hipMemsetAsync(h_p, 0, (size_t)BATCH*HID*2, stream);
  hipMemsetAsync(flags_p, 0, 16384, stream);
  hipMemsetAsync(zeros_p, 0, 4096, stream);

  cast_f2bf<<<4096,256,0,stream>>>(x, seq_p, T_STEPS*BATCH*DIM/4);
  cast_f2bf<<<2048,256,0,stream>>>(Whh, whhpl_p, NLAYER*HID*HID/4);

  for(int l=0;l<NLAYER;l++){
    transpose_cast<<<dim3(5*HID/32, DIM/32), dim3(32,8),0,stream>>>(
        Wx + (size_t)l*DIM*5*HID, wx_p + (size_t)l*5*HID*DIM, DIM, 5*HID);
    transpose_cast<<<dim3(HID/32, HID/32), dim3(32,8),0,stream>>>(
        Wmh + (size_t)l*HID*HID, wmh_p + (size_t)l*HID*HID, HID, HID);
    transpose_cast<<<dim3(HID/32, HID/32), dim3(32,8),0,stream>>>(
        Whh + (size_t)l*HID*HID, whh_p + (size_t)l*HID*HID, HID, HID);
    transpose_cast<<<dim3(3*HID/32, HID/32), dim3(32,8),0,stream>>>(
        Wg + (size_t)l*HID*3*HID, wg_p + (size_t)l*3*HID*HID, HID, 3*HID);
  }

  float* seq_out_f32 = out;
  float* hn_out = out + PS;
  float* cn_out = hn_out + (size_t)NLAYER*BATCH*HID;

  for(int l=0;l<NLAYER;l++){
    const u16* wg_l = wg_p + (size_t)l*3*HID*HID;
    bias2_kernel<<<768,256,0,stream>>>(wg_l, bhh + (size_t)l*HID, bg + (size_t)l*3*HID, bias2_p);
    // WhhG_t[3H][H] = (Wg^T @ Whh): (m@Whh)@Wg == m@WhhG
    gemm_bt<0><<<dim3(HID/128, 3*HID/128),256,0,stream>>>(
        wg_l, whhpl_p + (size_t)l*HID*HID, zeros_p, whhg_p,
        3*HID, HID, HID, nullptr);
    // packed xp planes [mi|hi|ii|oi|fi]
    gemm_bt<1><<<dim3(5*HID/128, (int)(TB/128)),256,0,stream>>>(
        seq_p, wx_p+(size_t)l*5*HID*DIM, bx + (size_t)l*5*HID, nullptr,
        (int)TB, 5*HID, DIM, pack_p);
    // planes[2..4] += xhi@Wg + bias2 (A read from packed plane 1)
    gemm_bt<2><<<dim3(3*HID/128, (int)(TB/128)),256,0,stream>>>(
        pack_p, wg_l, bias2_p, nullptr,
        (int)TB, 3*HID, HID, pack_p);

    const u16* wm_c = wmh_p + (size_t)l*HID*HID;
    const u16* wh_c = whh_p + (size_t)l*HID*HID;
    const u16* wG_c = whhg_p;
    const float* bmh_l = bmh + (size_t)l*HID;
    const float* bhh_l = bhh + (size_t)l*HID;
    u16* seqbf = (l==0)? seq_p : (u16*)nullptr;
    float* seqf = (l==0)? (float*)nullptr : seq_out_f32;
    float* hn_l = hn_out + (size_t)l*BATCH*HID;
    float* cn_l = cn_out + (size_t)l*BATCH*HID;
    u32* flags_l = flags_p + (size_t)l*2048;
    int is_first = (l==0)?1:0;

    mlstm_rec<<<dim3(64), dim3(256), 0, stream>>>(
        pack_p, wm_c, wh_c, wG_c, bmh_l, bhh_l,
        h_p, c_p, m_p,
        seqbf, seqf, hn_l, cn_l, flags_l, is_first);
  }
}

// Round 7
// 17343.803 us; speedup vs baseline: 3.2284x; 1.8110x over previous
//
#include <hip/hip_runtime.h>

#define T_STEPS 512
#define BATCH 64
#define DIM 1024
#define HID 1024
#define NLAYER 2
#define MFMA_B16 __builtin_amdgcn_mfma_f32_16x16x32_bf16

typedef __attribute__((ext_vector_type(8))) short bf16x8;
typedef __attribute__((ext_vector_type(4))) float f32x4;
typedef unsigned short u16;
typedef unsigned int u32;

__device__ inline float bf2f(u16 u){ u32 v=((u32)u)<<16; float f; __builtin_memcpy(&f,&v,4); return f; }
__device__ inline u16 f2bf(float f){ u32 u; __builtin_memcpy(&u,&f,4); u = (u + 0x7fffu + ((u>>16)&1u))>>16; return (u16)u; }
__device__ inline float sigm(float x){ return 1.f/(1.f+__expf(-x)); }

// Coherent (L2-bypassing) relaxed accessors.
__device__ inline u32 ld_cc(const u32* p){ return __hip_atomic_load(p, __ATOMIC_RELAXED, __HIP_MEMORY_SCOPE_SYSTEM); }
__device__ inline void st_cc(u32* p, u32 v){ __hip_atomic_store(p, v, __ATOMIC_RELAXED, __HIP_MEMORY_SCOPE_SYSTEM); }

// 8 wide coherent loads (512B span), one addr + imm offsets, no wait (caller waits).
__device__ __forceinline__ void ld8_sys(const u16* p, bf16x8* f){
  asm volatile(
    "global_load_dwordx4 %0, %8, off sc0 sc1\n\t"
    "global_load_dwordx4 %1, %8, off offset:64 sc0 sc1\n\t"
    "global_load_dwordx4 %2, %8, off offset:128 sc0 sc1\n\t"
    "global_load_dwordx4 %3, %8, off offset:192 sc0 sc1\n\t"
    "global_load_dwordx4 %4, %8, off offset:256 sc0 sc1\n\t"
    "global_load_dwordx4 %5, %8, off offset:320 sc0 sc1\n\t"
    "global_load_dwordx4 %6, %8, off offset:384 sc0 sc1\n\t"
    "global_load_dwordx4 %7, %8, off offset:448 sc0 sc1"
    : "=&v"(f[0]),"=&v"(f[1]),"=&v"(f[2]),"=&v"(f[3]),
      "=&v"(f[4]),"=&v"(f[5]),"=&v"(f[6]),"=&v"(f[7])
    : "v"(p)
    : "memory");
}
#define WAITV(S) do{ asm volatile("s_waitcnt vmcnt(" S ")" ::: "memory"); __builtin_amdgcn_sched_barrier(0); }while(0)

// ---------------- fp32 -> bf16 cast ----------------
__global__ void cast_f2bf(const float* __restrict__ src, u16* __restrict__ dst, int n4){
  int i = blockIdx.x*blockDim.x + threadIdx.x;
  int stride = gridDim.x*blockDim.x;
  for(; i<n4; i+=stride){
    float4 v = ((const float4*)src)[i];
    ushort4 o; o.x=f2bf(v.x); o.y=f2bf(v.y); o.z=f2bf(v.z); o.w=f2bf(v.w);
    ((ushort4*)dst)[i]=o;
  }
}

// ---------------- transpose + cast: src fp32 [R][C] -> dst bf16 [C][R] ----------------
__global__ void transpose_cast(const float* __restrict__ src, u16* __restrict__ dst, int R, int C){
  __shared__ float tile[32][33];
  int c0 = blockIdx.x*32, r0 = blockIdx.y*32;
  int tx = threadIdx.x, ty = threadIdx.y;
  for(int i=ty;i<32;i+=8) tile[i][tx] = src[(size_t)(r0+i)*C + c0+tx];
  __syncthreads();
  for(int i=ty;i<32;i+=8) dst[(size_t)(c0+i)*R + r0+tx] = f2bf(tile[tx][i]);
}

// ---------------- bias2 = bhh @ Wg + bg ----------------
__global__ void bias2_kernel(const u16* __restrict__ Wg_t, const float* __restrict__ bhh,
                             const float* __restrict__ bg, float* __restrict__ bias2){
  int w = (blockIdx.x*blockDim.x + threadIdx.x)>>6;
  int lane = threadIdx.x&63;
  if(w >= 3*HID) return;
  float s=0.f;
  for(int j=lane;j<HID;j+=64) s += bf2f(Wg_t[(size_t)w*HID + j]) * bhh[j];
  for(int off=32;off;off>>=1) s += __shfl_down(s, off);
  if(lane==0) bias2[w] = s + bg[w];
}

// ---------------- bf16 GEMM: C = A @ Bt^T + bias ----------------
// MODE 0: plain write. MODE 1: packed [t][cj][p][b][16c]. MODE 2: packed += (A from plane 1).
template<int MODE>
__launch_bounds__(256)
__global__ void gemm_bt(const u16* __restrict__ A, const u16* __restrict__ Bt,
                        const float* __restrict__ bias, u16* __restrict__ Cmat,
                        int M, int N, int K, u16* packed){
  __shared__ __align__(16) u16 As[128*32];
  __shared__ __align__(16) u16 Bs[128*32];
  const int tid=threadIdx.x, lane=tid&63, wave=tid>>6;
  const size_t m0 = (size_t)blockIdx.y*128, n0=(size_t)blockIdx.x*128;
  const int wr=wave>>1, wc=wave&1, fr=lane&15, fq=lane>>4;
  f32x4 acc[4][4];
  for(int m=0;m<4;m++) for(int n=0;n<4;n++) acc[m][n]=(f32x4){0.f,0.f,0.f,0.f};
  const int nk = K>>5;
  for(int kt=0;kt<nk;kt++){
    __syncthreads();
    for(int j=0;j<2;j++){
      int c = tid + j*256; int row=c>>2; int ko=(c&3)*8;
      if constexpr (MODE==2){
        size_t g = m0+row; int kc = kt*32+ko;
        size_t addr = (((g>>6)*64 + (size_t)(kc>>4))*5 + 1)*1024 + (g&63)*16 + (kc&15);
        *(int4*)&As[row*32+ko] = *(const int4*)&A[addr];
      } else {
        *(int4*)&As[row*32+ko] = *(const int4*)&A[(m0+row)*K + kt*32+ko];
      }
      *(int4*)&Bs[row*32+ko] = *(const int4*)&Bt[(n0+row)*K + kt*32+ko];
    }
    __syncthreads();
    bf16x8 af[4], bfv[4];
    for(int m=0;m<4;m++) af[m]=*(const bf16x8*)&As[(wr*64+m*16+fr)*32 + fq*8];
    for(int n=0;n<4;n++) bfv[n]=*(const bf16x8*)&Bs[(wc*64+n*16+fr)*32 + fq*8];
    for(int m=0;m<4;m++)
      for(int n=0;n<4;n++)
        acc[m][n]=MFMA_B16(af[m],bfv[n],acc[m][n],0,0,0);
  }
  for(int n=0;n<4;n++){
    size_t colg = n0 + wc*64+n*16+fr;
    float bv = bias[colg];
    for(int m=0;m<4;m++){
      for(int r=0;r<4;r++){
        size_t rowg = m0 + wr*64+m*16+fq*4+r;
        float v = acc[m][n][r]+bv;
        if constexpr (MODE==0){
          Cmat[rowg*N + colg] = f2bf(v);
        } else if constexpr (MODE==1){
          size_t p = colg>>10, pc = colg&1023;
          size_t t = rowg>>6, b = rowg&63, cj = pc>>4, c = pc&15;
          packed[((t*64+cj)*5 + p)*1024 + b*16 + c] = f2bf(v);
        } else {
          size_t pp = colg>>10, pc = colg&1023;
          size_t t = rowg>>6, b = rowg&63, cj = pc>>4, c = pc&15;
          u16* dst = packed + ((t*64+cj)*5 + (2+pp))*1024 + b*16 + c;
          *dst = f2bf(v + bf2f(*dst));
        }
      }
    }
  }
}

// ---------------- persistent recurrent kernel ----------------
// 64 blocks x 256 threads. Block cj owns cols [16cj,16cj+16); wave w owns rows
// [16w,16w+16). Wmh in VGPR/AGPR; stage-B weights (128KB) in XOR-swizzled LDS;
// h/m via batched wide sc0sc1 loads; xp via packed 10KB chunk -> LDS dbuf.
__launch_bounds__(256, 1)
__global__ void mlstm_rec(const u16* __restrict__ xp_pack,
   const u16* __restrict__ Wmh_t, const u16* __restrict__ Whh_t, const u16* __restrict__ WhhG_t,
   const float* __restrict__ bmh, const float* __restrict__ bhh,
   u16* h_buf, float* c_buf, u16* m_buf,
   u16* seq_bf, float* seq_f32, float* hn, float* cn, u32* flags, int is_first)
{
  __shared__ __align__(16) u16 wlds[64*1024];   // 128 KiB swizzled stage-B weights
  __shared__ __align__(16) u16 xl[2][5120];     // 20 KiB xp double-buffer
  const int tid=threadIdx.x, lane=tid&63, wave=tid>>6;
  const int cj = blockIdx.x, cb = cj*16;
  const int rowbase = wave*16;
  const int fr=lane&15, fq=lane>>4;
  const int col = cb+fr;
  const u32 a_off = (u32)(rowbase+fr)*HID + fq*8;
  const size_t w_off = (size_t)col*HID + fq*8;
  const u32 swz = ((u32)(fr&7))<<4;

  // ---- stage stage-B weights into swizzled LDS (once): 8192 x 16B chunks
  for(int it=0; it<32; ++it){
    int chunk = it*256 + tid;
    int cl = chunk >> 7;             // local col 0..63
    int kb = (chunk & 127) * 16;     // byte offset within col
    const u16* src;
    if(cl < 16) src = Whh_t + (size_t)(cb+cl)*HID;
    else { int g=(cl-16)>>4, j=cl&15; src = WhhG_t + (size_t)(g*HID + cb + j)*HID; }
    u32 dst = ((u32)cl*2048 + (u32)kb) ^ (((u32)cl&7)<<4);
    *(int4*)((char*)wlds + dst) = *(const int4*)((const char*)src + kb);
  }

  // ---- Wmh fragments into regs
  bf16x8 wmh[32];
  #pragma unroll
  for(int kt=0;kt<32;kt++) wmh[kt] = *(const bf16x8*)(Wmh_t + w_off + kt*32);

  float c_reg[4], h4[4];
  if(is_first){ for(int r=0;r<4;r++) c_reg[r]=0.f; }
  else { for(int r=0;r<4;r++) c_reg[r]=c_buf[(size_t)(rowbase+fq*4+r)*HID+col]; }
  for(int r=0;r<4;r++) h4[r]=0.f;

  const float bmh_c=bmh[col], bhh_c=bhh[col];
  u32 bar=0; int buf=0;

  { // xp chunk for t=0
    const int4* s0 = (const int4*)(xp_pack + (size_t)cj*5120);
    int4* d0 = (int4*)xl[0];
    d0[tid]=s0[tid]; d0[tid+256]=s0[tid+256]; if(tid<128) d0[tid+512]=s0[tid+512];
  }
  __syncthreads();

  for(int t=0;t<T_STEPS;t++){
    // ---- Stage A: m = xmi * (h @ Wmh + bmh)
    bf16x8 hf[32];
    const u16* hb = h_buf + a_off;
    ld8_sys(hb, hf); ld8_sys(hb+256, hf+8); ld8_sys(hb+512, hf+16); ld8_sys(hb+768, hf+24);
    // overlapped seq write of h(t-1) (4 stores, after the 32 loads in issue order)
    if(t>0){
      const size_t tbp=(size_t)(t-1)*BATCH*HID;
      #pragma unroll
      for(int r=0;r<4;r++){
        int b=rowbase+fq*4+r;
        if(seq_bf) seq_bf[tbp+(size_t)b*HID+col]=f2bf(h4[r]);
        else       seq_f32[tbp+(size_t)b*HID+col]=h4[r];
      }
    }
    f32x4 a0={0.f,0.f,0.f,0.f}, a1={0.f,0.f,0.f,0.f};
    if(t>0){ WAITV("28"); } else { WAITV("24"); }
    #pragma unroll
    for(int kt=0;kt<8;kt+=2){ a0=MFMA_B16(hf[kt],wmh[kt],a0,0,0,0); a1=MFMA_B16(hf[kt+1],wmh[kt+1],a1,0,0,0); }
    if(t>0){ WAITV("20"); } else { WAITV("16"); }
    #pragma unroll
    for(int kt=8;kt<16;kt+=2){ a0=MFMA_B16(hf[kt],wmh[kt],a0,0,0,0); a1=MFMA_B16(hf[kt+1],wmh[kt+1],a1,0,0,0); }
    if(t>0){ WAITV("12"); } else { WAITV("8"); }
    #pragma unroll
    for(int kt=16;kt<24;kt+=2){ a0=MFMA_B16(hf[kt],wmh[kt],a0,0,0,0); a1=MFMA_B16(hf[kt+1],wmh[kt+1],a1,0,0,0); }
    if(t>0){ WAITV("4"); } else { WAITV("0"); }
    #pragma unroll
    for(int kt=24;kt<32;kt+=2){ a0=MFMA_B16(hf[kt],wmh[kt],a0,0,0,0); a1=MFMA_B16(hf[kt+1],wmh[kt+1],a1,0,0,0); }
    #pragma unroll
    for(int r=0;r<4;r++){
      int b = rowbase+fq*4+r;
      float xmiv = bf2f(xl[buf][b*16+fr]);
      u32 my=(u32)f2bf(xmiv*(a0[r]+a1[r]+bmh_c));
      u32 ot=(u32)__shfl_xor((int)my,1);
      if((lane&1)==0) st_cc((u32*)(m_buf+(size_t)b*HID+col), my|(ot<<16));
    }
    // barrier (drain includes seq + m stores)
    asm volatile("s_waitcnt vmcnt(0)" ::: "memory");
    __syncthreads();
    if(tid==0) st_cc(&flags[(size_t)blockIdx.x*32], ++bar); else ++bar;
    if(tid<64){ while(ld_cc(&flags[(size_t)tid*32]) < bar){} }
    __syncthreads();

    // ---- Stage B: [g|i|o|f] = m @ [Whh|WhhG]_lds; gates; state update
    bf16x8 mf[32];
    const u16* mb = m_buf + a_off;
    ld8_sys(mb, mf); ld8_sys(mb+256, mf+8); ld8_sys(mb+512, mf+16); ld8_sys(mb+768, mf+24);
    int tn=(t+1<T_STEPS)?(t+1):t;
    const int4* s2=(const int4*)(xp_pack + (size_t)(tn*64+cj)*5120);
    int4 q0=s2[tid], q1=s2[tid+256], q2={0,0,0,0};
    if(tid<128) q2=s2[tid+512];
    f32x4 ag={0.f,0.f,0.f,0.f}, aiv={0.f,0.f,0.f,0.f}, aov={0.f,0.f,0.f,0.f}, afv={0.f,0.f,0.f,0.f};
    const char* wb = (const char*)wlds;
    WAITV("26");
    #pragma unroll
    for(int kt=0;kt<8;kt++){
      u32 kb = (u32)kt*64 + (u32)fq*16;
      bf16x8 w0=*(const bf16x8*)(wb + ((((u32)(fr   ))*2048 + kb) ^ swz));
      bf16x8 w1=*(const bf16x8*)(wb + ((((u32)(16+fr))*2048 + kb) ^ swz));
      bf16x8 w2=*(const bf16x8*)(wb + ((((u32)(32+fr))*2048 + kb) ^ swz));
      bf16x8 w3=*(const bf16x8*)(wb + ((((u32)(48+fr))*2048 + kb) ^ swz));
      ag =MFMA_B16(mf[kt],w0,ag ,0,0,0); aiv=MFMA_B16(mf[kt],w1,aiv,0,0,0);
      aov=MFMA_B16(mf[kt],w2,aov,0,0,0); afv=MFMA_B16(mf[kt],w3,afv,0,0,0);
    }
    WAITV("18");
    #pragma unroll
    for(int kt=8;kt<16;kt++){
      u32 kb = (u32)kt*64 + (u32)fq*16;
      bf16x8 w0=*(const bf16x8*)(wb + ((((u32)(fr   ))*2048 + kb) ^ swz));
      bf16x8 w1=*(const bf16x8*)(wb + ((((u32)(16+fr))*2048 + kb) ^ swz));
      bf16x8 w2=*(const bf16x8*)(wb + ((((u32)(32+fr))*2048 + kb) ^ swz));
      bf16x8 w3=*(const bf16x8*)(wb + ((((u32)(48+fr))*2048 + kb) ^ swz));
      ag =MFMA_B16(mf[kt],w0,ag ,0,0,0); aiv=MFMA_B16(mf[kt],w1,aiv,0,0,0);
      aov=MFMA_B16(mf[kt],w2,aov,0,0,0); afv=MFMA_B16(mf[kt],w3,afv,0,0,0);
    }
    WAITV("10");
    #pragma unroll
    for(int kt=16;kt<24;kt++){
      u32 kb = (u32)kt*64 + (u32)fq*16;
      bf16x8 w0=*(const bf16x8*)(wb + ((((u32)(fr   ))*2048 + kb) ^ swz));
      bf16x8 w1=*(const bf16x8*)(wb + ((((u32)(16+fr))*2048 + kb) ^ swz));
      bf16x8 w2=*(const bf16x8*)(wb + ((((u32)(32+fr))*2048 + kb) ^ swz));
      bf16x8 w3=*(const bf16x8*)(wb + ((((u32)(48+fr))*2048 + kb) ^ swz));
      ag =MFMA_B16(mf[kt],w0,ag ,0,0,0); aiv=MFMA_B16(mf[kt],w1,aiv,0,0,0);
      aov=MFMA_B16(mf[kt],w2,aov,0,0,0); afv=MFMA_B16(mf[kt],w3,afv,0,0,0);
    }
    WAITV("2");
    #pragma unroll
    for(int kt=24;kt<32;kt++){
      u32 kb = (u32)kt*64 + (u32)fq*16;
      bf16x8 w0=*(const bf16x8*)(wb + ((((u32)(fr   ))*2048 + kb) ^ swz));
      bf16x8 w1=*(const bf16x8*)(wb + ((((u32)(16+fr))*2048 + kb) ^ swz));
      bf16x8 w2=*(const bf16x8*)(wb + ((((u32)(32+fr))*2048 + kb) ^ swz));
      bf16x8 w3=*(const bf16x8*)(wb + ((((u32)(48+fr))*2048 + kb) ^ swz));
      ag =MFMA_B16(mf[kt],w0,ag ,0,0,0); aiv=MFMA_B16(mf[kt],w1,aiv,0,0,0);
      aov=MFMA_B16(mf[kt],w2,aov,0,0,0); afv=MFMA_B16(mf[kt],w3,afv,0,0,0);
    }
    #pragma unroll
    for(int r=0;r<4;r++){
      int b=rowbase+fq*4+r;
      float g  = ag[r]+bhh_c+bf2f(xl[buf][1024+b*16+fr]);
      float iv = sigm(aiv[r]+bf2f(xl[buf][2048+b*16+fr]));
      float ov = sigm(aov[r]+bf2f(xl[buf][3072+b*16+fr]));
      float fv = sigm(afv[r]+bf2f(xl[buf][4096+b*16+fr]));
      c_reg[r]=fv*c_reg[r]+iv*tanhf(g);
      h4[r]=tanhf(c_reg[r])*ov;
    }
    #pragma unroll
    for(int r=0;r<4;r++){
      int b=rowbase+fq*4+r;
      u32 my=(u32)f2bf(h4[r]);
      u32 ot=(u32)__shfl_xor((int)my,1);
      if((lane&1)==0) st_cc((u32*)(h_buf+(size_t)b*HID+col), my|(ot<<16));
    }
    { int4* d2=(int4*)xl[buf^1]; d2[tid]=q0; d2[tid+256]=q1; if(tid<128) d2[tid+512]=q2; }
    // barrier
    asm volatile("s_waitcnt vmcnt(0)" ::: "memory");
    __syncthreads();
    if(tid==0) st_cc(&flags[(size_t)blockIdx.x*32], ++bar); else ++bar;
    if(tid<64){ while(ld_cc(&flags[(size_t)tid*32]) < bar){} }
    __syncthreads();
    buf^=1;
  }
  // epilogue: seq[T-1], hn, cn
  const size_t tbl=(size_t)(T_STEPS-1)*BATCH*HID;
  for(int r=0;r<4;r++){
    int row=rowbase+fq*4+r;
    if(seq_bf) seq_bf[tbl+(size_t)row*HID+col]=f2bf(h4[r]);
    else       seq_f32[tbl+(size_t)row*HID+col]=h4[r];
    hn[(size_t)row*HID+col]=h4[r];
    cn[(size_t)row*HID+col]=c_reg[r];
    if(is_first) c_buf[(size_t)row*HID+col]=c_reg[r];
  }
}

extern "C" void kernel_launch(void* const* d_in, const int* in_sizes, int n_in,
                              void* d_out, int out_size, void* d_ws, size_t ws_size,
                              hipStream_t stream){
  const float* x   = (const float*)d_in[0];
  const float* Wx  = (const float*)d_in[1];
  const float* bx  = (const float*)d_in[2];
  const float* Wmh = (const float*)d_in[3];
  const float* bmh = (const float*)d_in[4];
  const float* Whh = (const float*)d_in[5];
  const float* bhh = (const float*)d_in[6];
  const float* Wg  = (const float*)d_in[7];
  const float* bg  = (const float*)d_in[8];
  float* out = (float*)d_out;
  char* ws = (char*)d_ws;

  const size_t TB = (size_t)T_STEPS*BATCH;
  const size_t PS = TB*HID;

  size_t off=0;
  auto alloc=[&](size_t b){ size_t o=off; off += (b+255)&~(size_t)255; return o; };
  size_t pack_off = alloc(5*PS*2);
  size_t seq_off  = alloc(PS*2);
  size_t wx_off   = alloc((size_t)NLAYER*5*HID*DIM*2);
  size_t wmh_off  = alloc((size_t)NLAYER*HID*HID*2);
  size_t whh_off  = alloc((size_t)NLAYER*HID*HID*2);
  size_t wg_off   = alloc((size_t)NLAYER*3*HID*HID*2);
  size_t whhp_off = alloc((size_t)NLAYER*HID*HID*2);
  size_t whhg_off = alloc((size_t)3*HID*HID*2);
  size_t bias2_off= alloc((size_t)3*HID*4);
  size_t zeros_off= alloc(4096);
  size_t h_off    = alloc((size_t)BATCH*HID*2);
  size_t m_off    = alloc((size_t)BATCH*HID*2);
  size_t c_off    = alloc((size_t)BATCH*HID*4);
  size_t flag_off = alloc(16384);
  (void)ws_size;

  u16* pack_p = (u16*)(ws+pack_off);
  u16* seq_p  = (u16*)(ws+seq_off);
  u16* wx_p   = (u16*)(ws+wx_off);
  u16* wmh_p  = (u16*)(ws+wmh_off);
  u16* whh_p  = (u16*)(ws+whh_off);
  u16* wg_p   = (u16*)(ws+wg_off);
  u16* whhpl_p= (u16*)(ws+whhp_off);
  u16* whhg_p = (u16*)(ws+whhg_off);
  float* bias2_p = (float*)(ws+bias2_off);
  float* zeros_p = (float*)(ws+zeros_off);
  u16* h_p  = (u16*)(ws+h_off);
  u16* m_p  = (u16*)(ws+m_off);
  float* c_p= (float*)(ws+c_off);
  u32* flags_p= (u32*)(ws+flag_off);

  hipMemsetAsync(h_p, 0, (size_t)BATCH*HID*2, stream);
  hipMemsetAsync(flags_p, 0, 16384, stream);
  hipMemsetAsync(zeros_p, 0, 4096, stream);

  cast_f2bf<<<4096,256,0,stream>>>(x, seq_p, T_STEPS*BATCH*DIM/4);
  cast_f2bf<<<2048,256,0,stream>>>(Whh, whhpl_p, NLAYER*HID*HID/4);

  for(int l=0;l<NLAYER;l++){
    transpose_cast<<<dim3(5*HID/32, DIM/32), dim3(32,8),0,stream>>>(
        Wx + (size_t)l*DIM*5*HID, wx_p + (size_t)l*5*HID*DIM, DIM, 5*HID);
    transpose_cast<<<dim3(HID/32, HID/32), dim3(32,8),0,stream>>>(
        Wmh + (size_t)l*HID*HID, wmh_p + (size_t)l*HID*HID, HID, HID);
    transpose_cast<<<dim3(HID/32, HID/32), dim3(32,8),0,stream>>>(
        Whh + (size_t)l*HID*HID, whh_p + (size_t)l*HID*HID, HID, HID);
    transpose_cast<<<dim3(3*HID/32, HID/32), dim3(32,8),0,stream>>>(
        Wg + (size_t)l*HID*3*HID, wg_p + (size_t)l*3*HID*HID, HID, 3*HID);
  }

  float* seq_out_f32 = out;
  float* hn_out = out + PS;
  float* cn_out = hn_out + (size_t)NLAYER*BATCH*HID;

  for(int l=0;l<NLAYER;l++){
    const u16* wg_l = wg_p + (size_t)l*3*HID*HID;
    bias2_kernel<<<768,256,0,stream>>>(wg_l, bhh + (size_t)l*HID, bg + (size_t)l*3*HID, bias2_p);
    gemm_bt<0><<<dim3(HID/128, 3*HID/128),256,0,stream>>>(
        wg_l, whhpl_p + (size_t)l*HID*HID, zeros_p, whhg_p,
        3*HID, HID, HID, nullptr);
    gemm_bt<1><<<dim3(5*HID/128, (int)(TB/128)),256,0,stream>>>(
        seq_p, wx_p+(size_t)l*5*HID*DIM, bx + (size_t)l*5*HID, nullptr,
        (int)TB, 5*HID, DIM, pack_p);
    gemm_bt<2><<<dim3(3*HID/128, (int)(TB/128)),256,0,stream>>>(
        pack_p, wg_l, bias2_p, nullptr,
        (int)TB, 3*HID, HID, pack_p);

    const u16* wm_c = wmh_p + (size_t)l*HID*HID;
    const u16* wh_c = whh_p + (size_t)l*HID*HID;
    const u16* wG_c = whhg_p;
    const float* bmh_l = bmh + (size_t)l*HID;
    const float* bhh_l = bhh + (size_t)l*HID;
    u16* seqbf = (l==0)? seq_p : (u16*)nullptr;
    float* seqf = (l==0)? (float*)nullptr : seq_out_f32;
    float* hn_l = hn_out + (size_t)l*BATCH*HID;
    float* cn_l = cn_out + (size_t)l*BATCH*HID;
    u32* flags_l = flags_p + (size_t)l*2048;
    int is_first = (l==0)?1:0;

    mlstm_rec<<<dim3(64), dim3(256), 0, stream>>>(
        pack_p, wm_c, wh_c, wG_c, bmh_l, bhh_l,
        h_p, c_p, m_p,
        seqbf, seqf, hn_l, cn_l, flags_l, is_first);
  }
}